// Round 20
// baseline (92.558 us; speedup 1.0000x reference)
//
#include <hip/hip_runtime.h>
#include <math.h>

#define DIM 256
#define NQ 48000
#define NCLS 126
#define BSZ 512
#define KNN 5
#define INV_TAU 14.285714285714286f
#define COEFF_V 0.1f
#define WARM 4000
#define NCH 750              /* 64-wide q chunks */
#define NBLK 188             /* 256-row hist/scatter blocks */
#define NBP 192              /* padded block count for scans */
#define NPREP 3032           /* (BSZ+NQ)/16 prep row-groups */
#define NGEMMB 375           /* gemm role blocks: one 512-thr block per qp */
#define NCS2B 504            /* cs2 role blocks: 2 parts per 512-thr block */
#define NEG_INF -3.402823466e38f

typedef __attribute__((ext_vector_type(8))) short bf16x8;
typedef __attribute__((ext_vector_type(4))) float f32x4;

__device__ __forceinline__ unsigned short f2bf(float f) {
    unsigned u = __float_as_uint(f);
    u += 0x7fffu + ((u >> 16) & 1u);
    return (unsigned short)(u >> 16);
}
__device__ __forceinline__ float bf2f(unsigned short h) {
    return __uint_as_float(((unsigned)h) << 16);
}

// fragment-tiled layout: 16-row x 32-col tiles of 1KB.
__device__ __forceinline__ size_t tidx(int r, int d) {
    return ((size_t)((r >> 4) * 8 + (d >> 5)) << 9)
         + (size_t)(((r & 15) * 4 + ((d >> 3) & 3)) << 3)
         + (size_t)(d & 7);
}

// branchless top-5 merge, compile-time indices only
__device__ __forceinline__ void merge5(float (&av)[KNN], int (&ai)[KNN],
                                       float (&bv)[KNN], int (&bi)[KNN]) {
    float rv[KNN]; int ri[KNN];
#pragma unroll
    for (int q = 0; q < KNN; ++q) {
        bool ta = (av[0] > bv[0]) || (av[0] == bv[0] && ai[0] < bi[0]);
        rv[q] = ta ? av[0] : bv[0];
        ri[q] = ta ? ai[0] : bi[0];
        if (q < KNN - 1) {
#pragma unroll
            for (int i = 0; i < KNN - 1; ++i) {
                float sav = av[i + 1], sbv = bv[i + 1];
                int   sai = ai[i + 1], sbi = bi[i + 1];
                av[i] = ta ? sav : av[i];  ai[i] = ta ? sai : ai[i];
                bv[i] = ta ? bv[i] : sbv;  bi[i] = ta ? bi[i] : sbi;
            }
        }
    }
#pragma unroll
    for (int q = 0; q < KNN; ++q) { av[q] = rv[q]; ai[q] = ri[q]; }
}

// per-thread sorted-desc insert of (s, idx)
__device__ __forceinline__ void ins5(float (&v)[KNN], int (&id)[KNN], float s, int jj) {
    if (s > v[KNN - 1] || (s == v[KNN - 1] && jj < id[KNN - 1])) {
        v[KNN - 1] = s; id[KNN - 1] = jj;
#pragma unroll
        for (int q = KNN - 1; q > 0; --q) {
            bool sw = (v[q] > v[q - 1]) || (v[q] == v[q - 1] && id[q] < id[q - 1]);
            if (sw) {
                float tv = v[q]; v[q] = v[q - 1]; v[q - 1] = tv;
                int ti = id[q]; id[q] = id[q - 1]; id[q - 1] = ti;
            }
        }
    }
}

// ---------- K0: prep (norm + pack, 16 rows/block) || per-block label hist ------------
__global__ __launch_bounds__(256) void k_prep(const float* __restrict__ feat,
                                              const float* __restrict__ queue,
                                              const int* __restrict__ slab,
                                              const int* __restrict__ qlab,
                                              unsigned short* __restrict__ Tt,
                                              unsigned short* __restrict__ Qt,
                                              int* __restrict__ pbh) {   // [126][192]
    __shared__ unsigned short st[16][264];
    __shared__ int h[NCLS];
    const int g = blockIdx.x;
    const int t = threadIdx.x;

    if (g >= NPREP) {
        // ---- hist role (parallel, 188 blocks)
        const int b = g - NPREP;
        if (t < NCLS) h[t] = 0;
        __syncthreads();
        int r = b * 256 + t;
        if (r < NQ) {
            int lb = (r < BSZ) ? slab[r] : qlab[r];
            atomicAdd(&h[lb], 1);
        }
        __syncthreads();
        if (t < NCLS) pbh[t * NBP + b] = h[t];
        return;
    }

    // ---- prep role
    const int rl = t >> 4, cl = t & 15;
    const float* src;
    unsigned short* dstb;
    if (g < 32) {
        src  = feat + (size_t)(BSZ + g * 16 + rl) * DIM;
        dstb = Tt + ((size_t)g << 12);
    } else {
        int q = (g - 32) * 16 + rl;
        src  = (q < BSZ) ? feat + (size_t)q * DIM : queue + (size_t)q * DIM;
        dstb = Qt + ((size_t)(g - 32) << 12);
    }
    float4 v[4];
#pragma unroll
    for (int i = 0; i < 4; ++i) v[i] = ((const float4*)src)[cl + i * 16];
    float ss = 0.0f;
#pragma unroll
    for (int i = 0; i < 4; ++i)
        ss += v[i].x * v[i].x + v[i].y * v[i].y + v[i].z * v[i].z + v[i].w * v[i].w;
#pragma unroll
    for (int off = 1; off <= 8; off <<= 1) ss += __shfl_xor(ss, off);
    float inv = 1.0f / fmaxf(sqrtf(ss), 1e-12f);
#pragma unroll
    for (int i = 0; i < 4; ++i) {
        ushort4 o = make_ushort4(f2bf(v[i].x * inv), f2bf(v[i].y * inv),
                                 f2bf(v[i].z * inv), f2bf(v[i].w * inv));
        *(ushort4*)&st[rl][(cl + i * 16) * 4] = o;
    }
    __syncthreads();
#pragma unroll
    for (int w = 0; w < 2; ++w) {
        int idx = t + w * 256;
        int j = idx >> 6, s = idx & 63;
        int r_in = s >> 2, d0 = j * 32 + (s & 3) * 8;
        *(uint4*)(dstb + (size_t)j * 512 + (size_t)s * 8) = *(const uint4*)&st[r_in][d0];
    }
}

// ---------- K1: per-class exclusive scan over blocks (126 parallel blocks) -----------
__global__ __launch_bounds__(NBP) void k_colscan(const int* __restrict__ pbh,
                                                 int* __restrict__ pboff,  // [126][192]
                                                 int* __restrict__ cnt) {
    __shared__ int s[NBP];
    const int c = blockIdx.x, b = threadIdx.x;
    int v = (b < NBLK) ? pbh[c * NBP + b] : 0;
    s[b] = v;
    __syncthreads();
#pragma unroll
    for (int d = 1; d < NBP; d <<= 1) {
        int add = (b >= d) ? s[b - d] : 0;
        __syncthreads();
        s[b] += add;
        __syncthreads();
    }
    if (b < NBLK) pboff[c * NBP + b] = s[b] - v;   // exclusive
    if (b == NBP - 1) cnt[c] = s[NBP - 1];
}

// ---------- K2: class-offset prefix (parallel load, LDS-speed serial scan) -----------
__global__ __launch_bounds__(128) void k_prefix2(const int* __restrict__ cnt,
                                                 int* __restrict__ off) {
    __shared__ int s[NCLS + 1];
    const int t = threadIdx.x;
    if (t < NCLS) s[t] = cnt[t];
    __syncthreads();
    if (t == 0) {
        int a = 0;
#pragma unroll
        for (int c = 0; c < NCLS; ++c) { int x = s[c]; s[c] = a; a += x; }
        s[NCLS] = a;
    }
    __syncthreads();
    if (t <= NCLS) off[t] = s[t];
}

// ---------- K3: scatter via block-local LDS ranks + class-local prefix ---------------
__global__ __launch_bounds__(256) void k_scatter2(const int* __restrict__ slab,
                                                  const int* __restrict__ qlab,
                                                  const int* __restrict__ off,
                                                  const int* __restrict__ pboff,
                                                  int* __restrict__ list) {
    __shared__ int h[NCLS];
    const int b = blockIdx.x, t = threadIdx.x;
    if (t < NCLS) h[t] = 0;
    __syncthreads();
    int r = b * 256 + t;
    if (r < NQ) {
        int lb = (r < BSZ) ? slab[r] : qlab[r];
        int rank = atomicAdd(&h[lb], 1);
        list[off[lb] + pboff[lb * NBP + b] + rank] = r;
    }
}

// ---------- K4: gemm (512-thr block, shared chunk stage) || cs2 ----------------------
// (512,1): min-occupancy 1 wave/EU lets the allocator keep the 128-reg B-panel
// WITHOUT spilling (round-19's 128-cap spill: WRITE 23MB).  Qt staged once per qp.
__global__ __launch_bounds__(512, 1) void k_main(const unsigned short* __restrict__ Tt,
                                                 const unsigned short* __restrict__ Qt,
                                                 const int* __restrict__ off,
                                                 const int* __restrict__ list,
                                                 float* __restrict__ pcs,    // [8][126][256]
                                                 float* __restrict__ pse,    // [512][750]
                                                 float* __restrict__ pmax) { // [512][750]
    __shared__ uint4 As4[4096];   // 64 KB: both q-chunks of this qp
    const int bid = blockIdx.x;
    const int t = threadIdx.x;

    if (bid >= NGEMMB) {
        // ---- cs2 role (504 blocks x 512 thr = 2 parts each)
        const int ci = bid - NGEMMB;             // 0..503
        const int c = ci >> 2;
        const int part = (ci & 3) * 2 + (t >> 8);
        const int d = t & 255;
        const int s1 = off[c + 1];
        float acc = 0.0f;
        int i = off[c] + part;
        for (; i + 56 < s1; i += 64) {
            float a0 = bf2f(Qt[tidx(list[i],      d)]);
            float a1 = bf2f(Qt[tidx(list[i + 8],  d)]);
            float a2 = bf2f(Qt[tidx(list[i + 16], d)]);
            float a3 = bf2f(Qt[tidx(list[i + 24], d)]);
            float a4 = bf2f(Qt[tidx(list[i + 32], d)]);
            float a5 = bf2f(Qt[tidx(list[i + 40], d)]);
            float a6 = bf2f(Qt[tidx(list[i + 48], d)]);
            float a7 = bf2f(Qt[tidx(list[i + 56], d)]);
            acc += ((a0 + a1) + (a2 + a3)) + ((a4 + a5) + (a6 + a7));
        }
        for (; i < s1; i += 8) acc += bf2f(Qt[tidx(list[i], d)]);
        pcs[((size_t)part * NCLS + c) * DIM + d] = acc;
        return;
    }

    // ---- gemm role: qp = bid; wave wid = tc (0..7)
    const int wid = t >> 6, lane = t & 63;
    const int qp = bid;
    const int tc = wid;
    const int c16 = lane & 15, g = lane >> 4;
    const int s = c16 * 4 + g;               // 16B unit within a 1KB tile
    const int sswz = s ^ ((s >> 3) & 7);     // swizzled unit (read side)
    const int lsw = lane ^ ((lane >> 3) & 7);// involution (source side)
    const uint4* srcu = (const uint4*)Qt + (size_t)qp * 4096;

    // stage both chunks (64 tiles of 1KB); each wave issues 8 DMA ops
#pragma unroll
    for (int it = 0; it < 8; ++it) {
        const int tile = it * 8 + wid;          // wave-uniform
        __builtin_amdgcn_global_load_lds(
            (const __attribute__((address_space(1))) void*)(srcu + tile * 64 + lsw),
            (__attribute__((address_space(3))) void*)&As4[tile * 64],
            16, 0, 0);
    }
    // B-panel loads (regs); drain together with stage at the barrier
    const unsigned short* Bb = Tt + ((size_t)(tc * 4) << 12) + (size_t)s * 8;
    bf16x8 bF[8][4];
#pragma unroll
    for (int ks = 0; ks < 8; ++ks)
#pragma unroll
        for (int nt = 0; nt < 4; ++nt)
            bF[ks][nt] = *(const bf16x8*)(Bb + (size_t)((nt * 8 + ks) << 9));
    __syncthreads();

#pragma unroll
    for (int qi = 0; qi < 2; ++qi) {
        const int qc = qp * 2 + qi;

        f32x4 acc[4][4];
#pragma unroll
        for (int a = 0; a < 4; ++a)
#pragma unroll
            for (int b = 0; b < 4; ++b) acc[a][b] = (f32x4){0.f, 0.f, 0.f, 0.f};

#pragma unroll
        for (int ks = 0; ks < 8; ++ks) {
            bf16x8 aF[4];
#pragma unroll
            for (int mq = 0; mq < 4; ++mq)
                aF[mq] = *(const bf16x8*)&As4[(qi * 32 + mq * 8 + ks) * 64 + sswz];
#pragma unroll
            for (int mq = 0; mq < 4; ++mq)
#pragma unroll
                for (int nt = 0; nt < 4; ++nt)
                    acc[mq][nt] = __builtin_amdgcn_mfma_f32_16x16x32_bf16(aF[mq], bF[ks][nt], acc[mq][nt], 0, 0, 0);
        }

#pragma unroll
        for (int nt = 0; nt < 4; ++nt) {
            float se = 0.0f, mx = NEG_INF;
#pragma unroll
            for (int mq = 0; mq < 4; ++mq)
#pragma unroll
                for (int j = 0; j < 4; ++j) {
                    float sv = acc[mq][nt][j];
                    se += __expf((sv - 1.0f) * INV_TAU);
                    mx = fmaxf(mx, sv);
                }
            se += __shfl_xor(se, 16); se += __shfl_xor(se, 32);
            mx = fmaxf(mx, __shfl_xor(mx, 16)); mx = fmaxf(mx, __shfl_xor(mx, 32));
            if (g == 0) {
                int tr = tc * 64 + nt * 16 + c16;
                pse[(size_t)tr * NCH + qc]  = se;
                pmax[(size_t)tr * NCH + qc] = mx;
            }
        }
    }
}

// ---------- K5: fused tail — chunk merge, rescan, vote, loss (w/ pcs reduce) ---------
__global__ __launch_bounds__(320) void k_tail(const unsigned short* __restrict__ Tt,
                                              const unsigned short* __restrict__ Qt,
                                              const float* __restrict__ pse,
                                              const float* __restrict__ pmax,
                                              const float* __restrict__ pcs,
                                              const int* __restrict__ cnt,
                                              const int* __restrict__ slab,
                                              const int* __restrict__ qlab,
                                              float* __restrict__ rowloss) {
    const int row = blockIdx.x, t = threadIdx.x;
    __shared__ float tn_sh[DIM];
    __shared__ float wse[5];
    __shared__ float wv[5][KNN]; __shared__ int wi[5][KNN];
    __shared__ int c5[KNN];
    __shared__ float s_lse;
    __shared__ float rv[5]; __shared__ int rq[5];
    __shared__ int winq, t5s[KNN], s_ps;
    __shared__ float dred[5];

    if (t < DIM) tn_sh[t] = bf2f(Tt[tidx(row, t)]);

    float v[KNN]; int id[KNN];
#pragma unroll
    for (int q = 0; q < KNN; ++q) { v[q] = NEG_INF; id[q] = 0x7fffffff; }
    float se = 0.0f;
    for (int c = t; c < NCH; c += 320) {
        se += pse[(size_t)row * NCH + c];
        ins5(v, id, pmax[(size_t)row * NCH + c], c);
    }
#pragma unroll
    for (int dist = 1; dist <= 32; dist <<= 1) {
        float ov[KNN]; int oi[KNN];
#pragma unroll
        for (int q = 0; q < KNN; ++q) { ov[q] = __shfl_xor(v[q], dist); oi[q] = __shfl_xor(id[q], dist); }
        se += __shfl_xor(se, dist);
        merge5(v, id, ov, oi);
    }
    if ((t & 63) == 0) {
        int w = t >> 6;
        wse[w] = se;
#pragma unroll
        for (int q = 0; q < KNN; ++q) { wv[w][q] = v[q]; wi[w][q] = id[q]; }
    }
    __syncthreads();
    if (t == 0) {
        float av[KNN]; int ai[KNN];
#pragma unroll
        for (int q = 0; q < KNN; ++q) { av[q] = wv[0][q]; ai[q] = wi[0][q]; }
        for (int w = 1; w < 5; ++w) {
            float bv[KNN]; int bi[KNN];
#pragma unroll
            for (int q = 0; q < KNN; ++q) { bv[q] = wv[w][q]; bi[q] = wi[w][q]; }
            merge5(av, ai, bv, bi);
        }
        float tot = wse[0] + wse[1] + wse[2] + wse[3] + wse[4];
        s_lse = logf(tot) + INV_TAU;
#pragma unroll
        for (int q = 0; q < KNN; ++q) c5[q] = ai[q];
    }
    __syncthreads();

    const int q = c5[t >> 6] * 64 + (t & 63);
    float dv = 0.0f;
    for (int d = 0; d < DIM; d += 8) {
        bf16x8 qv = *(const bf16x8*)(Qt + tidx(q, d));
#pragma unroll
        for (int e = 0; e < 8; ++e)
            dv = fmaf(bf2f((unsigned short)qv[e]), tn_sh[d + e], dv);
    }
    for (int k = 0; k < KNN; ++k) {
        float vv = dv; int qq = q;
#pragma unroll
        for (int d2 = 1; d2 <= 32; d2 <<= 1) {
            float ov = __shfl_xor(vv, d2); int oq = __shfl_xor(qq, d2);
            bool bet = (ov > vv) || (ov == vv && oq < qq);
            vv = bet ? ov : vv; qq = bet ? oq : qq;
        }
        if ((t & 63) == 0) { rv[t >> 6] = vv; rq[t >> 6] = qq; }
        __syncthreads();
        if (t == 0) {
            float bv = rv[0]; int bq = rq[0];
            for (int w = 1; w < 5; ++w) {
                bool bet = (rv[w] > bv) || (rv[w] == bv && rq[w] < bq);
                if (bet) { bv = rv[w]; bq = rq[w]; }
            }
            winq = bq; t5s[k] = bq;
        }
        __syncthreads();
        if (q == winq) dv = NEG_INF;
        __syncthreads();
    }
    if (t == 0) {
        int lab[KNN];
#pragma unroll
        for (int k = 0; k < KNN; ++k) {
            int j = t5s[k];
            lab[k] = (j < BSZ) ? slab[j] : qlab[j];
        }
        int bestc = 0, bestl = 0x7fffffff;
#pragma unroll
        for (int k = 0; k < KNN; ++k) {
            int c2 = 0;
#pragma unroll
            for (int w = 0; w < KNN; ++w) c2 += (lab[w] == lab[k]) ? 1 : 0;
            if (c2 > bestc || (c2 == bestc && lab[k] < bestl)) { bestc = c2; bestl = lab[k]; }
        }
        s_ps = bestl;
    }
    __syncthreads();

    // phase 3: CS[ps][t] = sum of 8 part partials (deterministic, atomic-free)
    const int ps = s_ps;
    float dd = 0.0f;
    if (t < DIM) {
        float cs = 0.0f;
#pragma unroll
        for (int p = 0; p < 8; ++p)
            cs += pcs[((size_t)p * NCLS + ps) * DIM + t];
        dd = tn_sh[t] * cs;
    }
#pragma unroll
    for (int o2 = 32; o2; o2 >>= 1) dd += __shfl_xor(dd, o2);
    if ((t & 63) == 0) dred[t >> 6] = dd;
    __syncthreads();
    if (t == 0) {
        float d = dred[0] + dred[1] + dred[2] + dred[3] + dred[4];
        float pc = (float)cnt[ps];
        rowloss[row] = -(d * INV_TAU - pc * s_lse) / fmaxf(pc, 1.0f);
    }
}

// ---------- K6: final reduction -------------------------------------------------------
__global__ __launch_bounds__(256) void k_final(const float* __restrict__ rowloss,
                                               const int* __restrict__ itp,
                                               float* __restrict__ out) {
    __shared__ float red[256];
    int t = threadIdx.x;
    red[t] = rowloss[t] + rowloss[t + 256];
    __syncthreads();
    for (int k = 128; k; k >>= 1) {
        if (t < k) red[t] += red[t + k];
        __syncthreads();
    }
    if (t == 0) out[0] = ((itp[0] > WARM) ? COEFF_V : 0.0f) * (red[0] / (float)BSZ);
}

// ---------- launcher ------------------------------------------------------------------
extern "C" void kernel_launch(void* const* d_in, const int* in_sizes, int n_in,
                              void* d_out, int out_size, void* d_ws, size_t ws_size,
                              hipStream_t stream) {
    const float* feat  = (const float*)d_in[0];
    const int*   slab  = (const int*)d_in[1];
    const int*   itp   = (const int*)d_in[2];
    const float* queue = (const float*)d_in[3];
    const int*   qlab  = (const int*)d_in[4];
    float* out = (float*)d_out;

    char* ws = (char*)d_ws;
    unsigned short* Qt = (unsigned short*)(ws);            // 24,576,000
    unsigned short* Tt = (unsigned short*)(ws + 24576000); //    262,144
    int*   cnt     = (int*)  (ws + 24838144);              //        512
    int*   off     = (int*)  (ws + 24838656);              //        512
    int*   list    = (int*)  (ws + 24839168);              //    192,000
    int*   pbh     = (int*)  (ws + 25031168);              //     96,768
    int*   pboff   = (int*)  (ws + 25127936);              //     96,768
    float* pcs     = (float*)(ws + 25224704);              //  1,032,192 (8*126*256*4)
    float* pse     = (float*)(ws + 26256896);              //  1,536,000
    float* pmax    = (float*)(ws + 27792896);              //  1,536,000
    float* rowloss = (float*)(ws + 29328896);              //      2,048

    hipLaunchKernelGGL(k_prep, dim3(NPREP + NBLK), dim3(256), 0, stream,
                       feat, queue, slab, qlab, Tt, Qt, pbh);
    hipLaunchKernelGGL(k_colscan, dim3(NCLS), dim3(NBP), 0, stream, pbh, pboff, cnt);
    hipLaunchKernelGGL(k_prefix2, dim3(1), dim3(128), 0, stream, cnt, off);
    hipLaunchKernelGGL(k_scatter2, dim3(NBLK), dim3(256), 0, stream, slab, qlab, off, pboff, list);
    hipLaunchKernelGGL(k_main, dim3(NGEMMB + NCS2B), dim3(512), 0, stream,
                       Tt, Qt, off, list, pcs, pse, pmax);
    hipLaunchKernelGGL(k_tail, dim3(BSZ), dim3(320), 0, stream,
                       Tt, Qt, pse, pmax, pcs, cnt, slab, qlab, rowloss);
    hipLaunchKernelGGL(k_final, dim3(1), dim3(256), 0, stream, rowloss, itp, out);
}

// Round 21
// 88.755 us; speedup vs baseline: 1.0428x; 1.0428x over previous
//
#include <hip/hip_runtime.h>
#include <math.h>

#define DIM 256
#define NQ 48000
#define NCLS 126
#define BSZ 512
#define KNN 5
#define INV_TAU 14.285714285714286f
#define COEFF_V 0.1f
#define WARM 4000
#define NCH 750              /* 64-wide q chunks */
#define NBLK 188             /* 256-row hist/scatter blocks */
#define NBP 192              /* padded block count for scans */
#define NPREP 3032           /* (BSZ+NQ)/16 prep row-groups */
#define NGEMMB 375           /* gemm role blocks: one 512-thr block per qp */
#define NCS2B 504            /* cs2 role blocks: 2 parts per 512-thr block */
#define NEG_INF -3.402823466e38f

typedef __attribute__((ext_vector_type(8))) short bf16x8;
typedef __attribute__((ext_vector_type(4))) float f32x4;

__device__ __forceinline__ unsigned short f2bf(float f) {
    unsigned u = __float_as_uint(f);
    u += 0x7fffu + ((u >> 16) & 1u);
    return (unsigned short)(u >> 16);
}
__device__ __forceinline__ float bf2f(unsigned short h) {
    return __uint_as_float(((unsigned)h) << 16);
}

// fragment-tiled layout: 16-row x 32-col tiles of 1KB.
__device__ __forceinline__ size_t tidx(int r, int d) {
    return ((size_t)((r >> 4) * 8 + (d >> 5)) << 9)
         + (size_t)(((r & 15) * 4 + ((d >> 3) & 3)) << 3)
         + (size_t)(d & 7);
}

// branchless top-5 merge, compile-time indices only
__device__ __forceinline__ void merge5(float (&av)[KNN], int (&ai)[KNN],
                                       float (&bv)[KNN], int (&bi)[KNN]) {
    float rv[KNN]; int ri[KNN];
#pragma unroll
    for (int q = 0; q < KNN; ++q) {
        bool ta = (av[0] > bv[0]) || (av[0] == bv[0] && ai[0] < bi[0]);
        rv[q] = ta ? av[0] : bv[0];
        ri[q] = ta ? ai[0] : bi[0];
        if (q < KNN - 1) {
#pragma unroll
            for (int i = 0; i < KNN - 1; ++i) {
                float sav = av[i + 1], sbv = bv[i + 1];
                int   sai = ai[i + 1], sbi = bi[i + 1];
                av[i] = ta ? sav : av[i];  ai[i] = ta ? sai : ai[i];
                bv[i] = ta ? bv[i] : sbv;  bi[i] = ta ? bi[i] : sbi;
            }
        }
    }
#pragma unroll
    for (int q = 0; q < KNN; ++q) { av[q] = rv[q]; ai[q] = ri[q]; }
}

// per-thread sorted-desc insert of (s, idx)
__device__ __forceinline__ void ins5(float (&v)[KNN], int (&id)[KNN], float s, int jj) {
    if (s > v[KNN - 1] || (s == v[KNN - 1] && jj < id[KNN - 1])) {
        v[KNN - 1] = s; id[KNN - 1] = jj;
#pragma unroll
        for (int q = KNN - 1; q > 0; --q) {
            bool sw = (v[q] > v[q - 1]) || (v[q] == v[q - 1] && id[q] < id[q - 1]);
            if (sw) {
                float tv = v[q]; v[q] = v[q - 1]; v[q - 1] = tv;
                int ti = id[q]; id[q] = id[q - 1]; id[q - 1] = ti;
            }
        }
    }
}

// ---------- K0: prep (norm + pack, 16 rows/block) || per-block label hist ------------
__global__ __launch_bounds__(256) void k_prep(const float* __restrict__ feat,
                                              const float* __restrict__ queue,
                                              const int* __restrict__ slab,
                                              const int* __restrict__ qlab,
                                              unsigned short* __restrict__ Tt,
                                              unsigned short* __restrict__ Qt,
                                              int* __restrict__ pbh) {   // [126][192]
    __shared__ unsigned short st[16][264];
    __shared__ int h[NCLS];
    const int g = blockIdx.x;
    const int t = threadIdx.x;

    if (g >= NPREP) {
        // ---- hist role (parallel, 188 blocks)
        const int b = g - NPREP;
        if (t < NCLS) h[t] = 0;
        __syncthreads();
        int r = b * 256 + t;
        if (r < NQ) {
            int lb = (r < BSZ) ? slab[r] : qlab[r];
            atomicAdd(&h[lb], 1);
        }
        __syncthreads();
        if (t < NCLS) pbh[t * NBP + b] = h[t];
        return;
    }

    // ---- prep role
    const int rl = t >> 4, cl = t & 15;
    const float* src;
    unsigned short* dstb;
    if (g < 32) {
        src  = feat + (size_t)(BSZ + g * 16 + rl) * DIM;
        dstb = Tt + ((size_t)g << 12);
    } else {
        int q = (g - 32) * 16 + rl;
        src  = (q < BSZ) ? feat + (size_t)q * DIM : queue + (size_t)q * DIM;
        dstb = Qt + ((size_t)(g - 32) << 12);
    }
    float4 v[4];
#pragma unroll
    for (int i = 0; i < 4; ++i) v[i] = ((const float4*)src)[cl + i * 16];
    float ss = 0.0f;
#pragma unroll
    for (int i = 0; i < 4; ++i)
        ss += v[i].x * v[i].x + v[i].y * v[i].y + v[i].z * v[i].z + v[i].w * v[i].w;
#pragma unroll
    for (int off = 1; off <= 8; off <<= 1) ss += __shfl_xor(ss, off);
    float inv = 1.0f / fmaxf(sqrtf(ss), 1e-12f);
#pragma unroll
    for (int i = 0; i < 4; ++i) {
        ushort4 o = make_ushort4(f2bf(v[i].x * inv), f2bf(v[i].y * inv),
                                 f2bf(v[i].z * inv), f2bf(v[i].w * inv));
        *(ushort4*)&st[rl][(cl + i * 16) * 4] = o;
    }
    __syncthreads();
#pragma unroll
    for (int w = 0; w < 2; ++w) {
        int idx = t + w * 256;
        int j = idx >> 6, s = idx & 63;
        int r_in = s >> 2, d0 = j * 32 + (s & 3) * 8;
        *(uint4*)(dstb + (size_t)j * 512 + (size_t)s * 8) = *(const uint4*)&st[r_in][d0];
    }
}

// ---------- K1: per-class exclusive scan over blocks (126 parallel blocks) -----------
__global__ __launch_bounds__(NBP) void k_colscan(const int* __restrict__ pbh,
                                                 int* __restrict__ pboff,  // [126][192]
                                                 int* __restrict__ cnt) {
    __shared__ int s[NBP];
    const int c = blockIdx.x, b = threadIdx.x;
    int v = (b < NBLK) ? pbh[c * NBP + b] : 0;
    s[b] = v;
    __syncthreads();
#pragma unroll
    for (int d = 1; d < NBP; d <<= 1) {
        int add = (b >= d) ? s[b - d] : 0;
        __syncthreads();
        s[b] += add;
        __syncthreads();
    }
    if (b < NBLK) pboff[c * NBP + b] = s[b] - v;   // exclusive
    if (b == NBP - 1) cnt[c] = s[NBP - 1];
}

// ---------- K2: class-offset prefix (parallel load, LDS-speed serial scan) -----------
__global__ __launch_bounds__(128) void k_prefix2(const int* __restrict__ cnt,
                                                 int* __restrict__ off) {
    __shared__ int s[NCLS + 1];
    const int t = threadIdx.x;
    if (t < NCLS) s[t] = cnt[t];
    __syncthreads();
    if (t == 0) {
        int a = 0;
#pragma unroll
        for (int c = 0; c < NCLS; ++c) { int x = s[c]; s[c] = a; a += x; }
        s[NCLS] = a;
    }
    __syncthreads();
    if (t <= NCLS) off[t] = s[t];
}

// ---------- K3: scatter via block-local LDS ranks + class-local prefix ---------------
__global__ __launch_bounds__(256) void k_scatter2(const int* __restrict__ slab,
                                                  const int* __restrict__ qlab,
                                                  const int* __restrict__ off,
                                                  const int* __restrict__ pboff,
                                                  int* __restrict__ list) {
    __shared__ int h[NCLS];
    const int b = blockIdx.x, t = threadIdx.x;
    if (t < NCLS) h[t] = 0;
    __syncthreads();
    int r = b * 256 + t;
    if (r < NQ) {
        int lb = (r < BSZ) ? slab[r] : qlab[r];
        int rank = atomicAdd(&h[lb], 1);
        list[off[lb] + pboff[lb * NBP + b] + rank] = r;
    }
}

// ---------- K4: gemm (512-thr, shared stage, nt-split regs: NO spill) || cs2 ---------
// nt processed in 2 halves: bF[8][2](64) + acc[4][2](32) + aF(16) ~ 115 regs < 128.
// Epilogue is per-nt independent so the split is exact.  B-panel loaded 2x (L2-hot).
__global__ __launch_bounds__(512, 1) void k_main(const unsigned short* __restrict__ Tt,
                                                 const unsigned short* __restrict__ Qt,
                                                 const int* __restrict__ off,
                                                 const int* __restrict__ list,
                                                 float* __restrict__ pcs,    // [8][126][256]
                                                 float* __restrict__ pse,    // [512][750]
                                                 float* __restrict__ pmax) { // [512][750]
    __shared__ uint4 As4[4096];   // 64 KB: both q-chunks of this qp
    const int bid = blockIdx.x;
    const int t = threadIdx.x;

    if (bid >= NGEMMB) {
        // ---- cs2 role (504 blocks x 512 thr = 2 parts each)
        const int ci = bid - NGEMMB;             // 0..503
        const int c = ci >> 2;
        const int part = (ci & 3) * 2 + (t >> 8);
        const int d = t & 255;
        const int s1 = off[c + 1];
        float acc = 0.0f;
        int i = off[c] + part;
        for (; i + 56 < s1; i += 64) {
            float a0 = bf2f(Qt[tidx(list[i],      d)]);
            float a1 = bf2f(Qt[tidx(list[i + 8],  d)]);
            float a2 = bf2f(Qt[tidx(list[i + 16], d)]);
            float a3 = bf2f(Qt[tidx(list[i + 24], d)]);
            float a4 = bf2f(Qt[tidx(list[i + 32], d)]);
            float a5 = bf2f(Qt[tidx(list[i + 40], d)]);
            float a6 = bf2f(Qt[tidx(list[i + 48], d)]);
            float a7 = bf2f(Qt[tidx(list[i + 56], d)]);
            acc += ((a0 + a1) + (a2 + a3)) + ((a4 + a5) + (a6 + a7));
        }
        for (; i < s1; i += 8) acc += bf2f(Qt[tidx(list[i], d)]);
        pcs[((size_t)part * NCLS + c) * DIM + d] = acc;
        return;
    }

    // ---- gemm role: qp = bid; wave wid = tc (0..7)
    const int wid = t >> 6, lane = t & 63;
    const int qp = bid;
    const int tc = wid;
    const int c16 = lane & 15, g = lane >> 4;
    const int s = c16 * 4 + g;               // 16B unit within a 1KB tile
    const int sswz = s ^ ((s >> 3) & 7);     // swizzled unit (read side)
    const int lsw = lane ^ ((lane >> 3) & 7);// involution (source side)
    const uint4* srcu = (const uint4*)Qt + (size_t)qp * 4096;

    // stage both chunks (64 tiles of 1KB); each wave issues 8 DMA ops
#pragma unroll
    for (int it = 0; it < 8; ++it) {
        const int tile = it * 8 + wid;          // wave-uniform
        __builtin_amdgcn_global_load_lds(
            (const __attribute__((address_space(1))) void*)(srcu + tile * 64 + lsw),
            (__attribute__((address_space(3))) void*)&As4[tile * 64],
            16, 0, 0);
    }
    const unsigned short* Bb = Tt + ((size_t)(tc * 4) << 12) + (size_t)s * 8;
    __syncthreads();

#pragma unroll
    for (int nth = 0; nth < 2; ++nth) {
        // half B-panel: nt = nth*2 + {0,1}
        bf16x8 bF[8][2];
#pragma unroll
        for (int ks = 0; ks < 8; ++ks)
#pragma unroll
            for (int n2 = 0; n2 < 2; ++n2)
                bF[ks][n2] = *(const bf16x8*)(Bb + (size_t)(((nth * 2 + n2) * 8 + ks) << 9));

#pragma unroll
        for (int qi = 0; qi < 2; ++qi) {
            const int qc = qp * 2 + qi;

            f32x4 acc[4][2];
#pragma unroll
            for (int a = 0; a < 4; ++a)
#pragma unroll
                for (int b = 0; b < 2; ++b) acc[a][b] = (f32x4){0.f, 0.f, 0.f, 0.f};

#pragma unroll
            for (int ks = 0; ks < 8; ++ks) {
                bf16x8 aF[4];
#pragma unroll
                for (int mq = 0; mq < 4; ++mq)
                    aF[mq] = *(const bf16x8*)&As4[(qi * 32 + mq * 8 + ks) * 64 + sswz];
#pragma unroll
                for (int mq = 0; mq < 4; ++mq)
#pragma unroll
                    for (int n2 = 0; n2 < 2; ++n2)
                        acc[mq][n2] = __builtin_amdgcn_mfma_f32_16x16x32_bf16(aF[mq], bF[ks][n2], acc[mq][n2], 0, 0, 0);
            }

#pragma unroll
            for (int n2 = 0; n2 < 2; ++n2) {
                const int nt = nth * 2 + n2;
                float se = 0.0f, mx = NEG_INF;
#pragma unroll
                for (int mq = 0; mq < 4; ++mq)
#pragma unroll
                    for (int j = 0; j < 4; ++j) {
                        float sv = acc[mq][n2][j];
                        se += __expf((sv - 1.0f) * INV_TAU);
                        mx = fmaxf(mx, sv);
                    }
                se += __shfl_xor(se, 16); se += __shfl_xor(se, 32);
                mx = fmaxf(mx, __shfl_xor(mx, 16)); mx = fmaxf(mx, __shfl_xor(mx, 32));
                if (g == 0) {
                    int tr = tc * 64 + nt * 16 + c16;
                    pse[(size_t)tr * NCH + qc]  = se;
                    pmax[(size_t)tr * NCH + qc] = mx;
                }
            }
        }
    }
}

// ---------- K5: fused tail — chunk merge, rescan, vote, loss (w/ pcs reduce) ---------
__global__ __launch_bounds__(320) void k_tail(const unsigned short* __restrict__ Tt,
                                              const unsigned short* __restrict__ Qt,
                                              const float* __restrict__ pse,
                                              const float* __restrict__ pmax,
                                              const float* __restrict__ pcs,
                                              const int* __restrict__ cnt,
                                              const int* __restrict__ slab,
                                              const int* __restrict__ qlab,
                                              float* __restrict__ rowloss) {
    const int row = blockIdx.x, t = threadIdx.x;
    __shared__ float tn_sh[DIM];
    __shared__ float wse[5];
    __shared__ float wv[5][KNN]; __shared__ int wi[5][KNN];
    __shared__ int c5[KNN];
    __shared__ float s_lse;
    __shared__ float rv[5]; __shared__ int rq[5];
    __shared__ int winq, t5s[KNN], s_ps;
    __shared__ float dred[5];

    if (t < DIM) tn_sh[t] = bf2f(Tt[tidx(row, t)]);

    float v[KNN]; int id[KNN];
#pragma unroll
    for (int q = 0; q < KNN; ++q) { v[q] = NEG_INF; id[q] = 0x7fffffff; }
    float se = 0.0f;
    for (int c = t; c < NCH; c += 320) {
        se += pse[(size_t)row * NCH + c];
        ins5(v, id, pmax[(size_t)row * NCH + c], c);
    }
#pragma unroll
    for (int dist = 1; dist <= 32; dist <<= 1) {
        float ov[KNN]; int oi[KNN];
#pragma unroll
        for (int q = 0; q < KNN; ++q) { ov[q] = __shfl_xor(v[q], dist); oi[q] = __shfl_xor(id[q], dist); }
        se += __shfl_xor(se, dist);
        merge5(v, id, ov, oi);
    }
    if ((t & 63) == 0) {
        int w = t >> 6;
        wse[w] = se;
#pragma unroll
        for (int q = 0; q < KNN; ++q) { wv[w][q] = v[q]; wi[w][q] = id[q]; }
    }
    __syncthreads();
    if (t == 0) {
        float av[KNN]; int ai[KNN];
#pragma unroll
        for (int q = 0; q < KNN; ++q) { av[q] = wv[0][q]; ai[q] = wi[0][q]; }
        for (int w = 1; w < 5; ++w) {
            float bv[KNN]; int bi[KNN];
#pragma unroll
            for (int q = 0; q < KNN; ++q) { bv[q] = wv[w][q]; bi[q] = wi[w][q]; }
            merge5(av, ai, bv, bi);
        }
        float tot = wse[0] + wse[1] + wse[2] + wse[3] + wse[4];
        s_lse = logf(tot) + INV_TAU;
#pragma unroll
        for (int q = 0; q < KNN; ++q) c5[q] = ai[q];
    }
    __syncthreads();

    const int q = c5[t >> 6] * 64 + (t & 63);
    float dv = 0.0f;
    for (int d = 0; d < DIM; d += 8) {
        bf16x8 qv = *(const bf16x8*)(Qt + tidx(q, d));
#pragma unroll
        for (int e = 0; e < 8; ++e)
            dv = fmaf(bf2f((unsigned short)qv[e]), tn_sh[d + e], dv);
    }
    for (int k = 0; k < KNN; ++k) {
        float vv = dv; int qq = q;
#pragma unroll
        for (int d2 = 1; d2 <= 32; d2 <<= 1) {
            float ov = __shfl_xor(vv, d2); int oq = __shfl_xor(qq, d2);
            bool bet = (ov > vv) || (ov == vv && oq < qq);
            vv = bet ? ov : vv; qq = bet ? oq : qq;
        }
        if ((t & 63) == 0) { rv[t >> 6] = vv; rq[t >> 6] = qq; }
        __syncthreads();
        if (t == 0) {
            float bv = rv[0]; int bq = rq[0];
            for (int w = 1; w < 5; ++w) {
                bool bet = (rv[w] > bv) || (rv[w] == bv && rq[w] < bq);
                if (bet) { bv = rv[w]; bq = rq[w]; }
            }
            winq = bq; t5s[k] = bq;
        }
        __syncthreads();
        if (q == winq) dv = NEG_INF;
        __syncthreads();
    }
    if (t == 0) {
        int lab[KNN];
#pragma unroll
        for (int k = 0; k < KNN; ++k) {
            int j = t5s[k];
            lab[k] = (j < BSZ) ? slab[j] : qlab[j];
        }
        int bestc = 0, bestl = 0x7fffffff;
#pragma unroll
        for (int k = 0; k < KNN; ++k) {
            int c2 = 0;
#pragma unroll
            for (int w = 0; w < KNN; ++w) c2 += (lab[w] == lab[k]) ? 1 : 0;
            if (c2 > bestc || (c2 == bestc && lab[k] < bestl)) { bestc = c2; bestl = lab[k]; }
        }
        s_ps = bestl;
    }
    __syncthreads();

    // phase 3: CS[ps][t] = sum of 8 part partials (deterministic, atomic-free)
    const int ps = s_ps;
    float dd = 0.0f;
    if (t < DIM) {
        float cs = 0.0f;
#pragma unroll
        for (int p = 0; p < 8; ++p)
            cs += pcs[((size_t)p * NCLS + ps) * DIM + t];
        dd = tn_sh[t] * cs;
    }
#pragma unroll
    for (int o2 = 32; o2; o2 >>= 1) dd += __shfl_xor(dd, o2);
    if ((t & 63) == 0) dred[t >> 6] = dd;
    __syncthreads();
    if (t == 0) {
        float d = dred[0] + dred[1] + dred[2] + dred[3] + dred[4];
        float pc = (float)cnt[ps];
        rowloss[row] = -(d * INV_TAU - pc * s_lse) / fmaxf(pc, 1.0f);
    }
}

// ---------- K6: final reduction -------------------------------------------------------
__global__ __launch_bounds__(256) void k_final(const float* __restrict__ rowloss,
                                               const int* __restrict__ itp,
                                               float* __restrict__ out) {
    __shared__ float red[256];
    int t = threadIdx.x;
    red[t] = rowloss[t] + rowloss[t + 256];
    __syncthreads();
    for (int k = 128; k; k >>= 1) {
        if (t < k) red[t] += red[t + k];
        __syncthreads();
    }
    if (t == 0) out[0] = ((itp[0] > WARM) ? COEFF_V : 0.0f) * (red[0] / (float)BSZ);
}

// ---------- launcher ------------------------------------------------------------------
extern "C" void kernel_launch(void* const* d_in, const int* in_sizes, int n_in,
                              void* d_out, int out_size, void* d_ws, size_t ws_size,
                              hipStream_t stream) {
    const float* feat  = (const float*)d_in[0];
    const int*   slab  = (const int*)d_in[1];
    const int*   itp   = (const int*)d_in[2];
    const float* queue = (const float*)d_in[3];
    const int*   qlab  = (const int*)d_in[4];
    float* out = (float*)d_out;

    char* ws = (char*)d_ws;
    unsigned short* Qt = (unsigned short*)(ws);            // 24,576,000
    unsigned short* Tt = (unsigned short*)(ws + 24576000); //    262,144
    int*   cnt     = (int*)  (ws + 24838144);              //        512
    int*   off     = (int*)  (ws + 24838656);              //        512
    int*   list    = (int*)  (ws + 24839168);              //    192,000
    int*   pbh     = (int*)  (ws + 25031168);              //     96,768
    int*   pboff   = (int*)  (ws + 25127936);              //     96,768
    float* pcs     = (float*)(ws + 25224704);              //  1,032,192 (8*126*256*4)
    float* pse     = (float*)(ws + 26256896);              //  1,536,000
    float* pmax    = (float*)(ws + 27792896);              //  1,536,000
    float* rowloss = (float*)(ws + 29328896);              //      2,048

    hipLaunchKernelGGL(k_prep, dim3(NPREP + NBLK), dim3(256), 0, stream,
                       feat, queue, slab, qlab, Tt, Qt, pbh);
    hipLaunchKernelGGL(k_colscan, dim3(NCLS), dim3(NBP), 0, stream, pbh, pboff, cnt);
    hipLaunchKernelGGL(k_prefix2, dim3(1), dim3(128), 0, stream, cnt, off);
    hipLaunchKernelGGL(k_scatter2, dim3(NBLK), dim3(256), 0, stream, slab, qlab, off, pboff, list);
    hipLaunchKernelGGL(k_main, dim3(NGEMMB + NCS2B), dim3(512), 0, stream,
                       Tt, Qt, off, list, pcs, pse, pmax);
    hipLaunchKernelGGL(k_tail, dim3(BSZ), dim3(320), 0, stream,
                       Tt, Qt, pse, pmax, pcs, cnt, slab, qlab, rowloss);
    hipLaunchKernelGGL(k_final, dim3(1), dim3(256), 0, stream, rowloss, itp, out);
}